// Round 20
// baseline (173.031 us; speedup 1.0000x reference)
//
#include <hip/hip_runtime.h>
#include <hip/hip_bf16.h>

typedef __attribute__((ext_vector_type(8))) short s16x8;
typedef __attribute__((ext_vector_type(4))) float f32x4;
typedef __attribute__((ext_vector_type(2))) float pf2;

#define D_FEAT 512
#define SLICES 8
#define SLICE_D 64
#define ROWS 80  // rows per mlp block: grid = 20000/80 = 250 = 0.98 blocks/CU (no tail)

__device__ __forceinline__ unsigned short f2bf(float f) {
  __hip_bfloat16 h = __float2bfloat16(f);
  return *reinterpret_cast<unsigned short*>(&h);
}

__device__ __forceinline__ float bitsf(unsigned int u) {
  union { unsigned int i; float f; } c;
  c.i = u;
  return c.f;
}

__device__ __forceinline__ void async16(void* lds, const void* g) {
  __builtin_amdgcn_global_load_lds(
      (const __attribute__((address_space(1))) void*)g,
      (__attribute__((address_space(3))) void*)lds, 16, 0, 0);
}

// ---------------- zero scratch ----------------

__global__ __launch_bounds__(256) void zero_k(int4* __restrict__ p, int n16) {
  int i = blockIdx.x * 256 + threadIdx.x;
  if (i < n16) p[i] = make_int4(0, 0, 0, 0);
}

// ---------------- histogram (deg), 4 edges/thread ----------------

__global__ __launch_bounds__(256) void hx_k(const int* __restrict__ dst, int E,
                                            int* __restrict__ deg) {
  int i4 = (blockIdx.x * 256 + threadIdx.x) * 4;
  if (i4 + 3 < E) {
    int4 d4 = *(const int4*)&dst[i4];
    atomicAdd(&deg[d4.x], 1);
    atomicAdd(&deg[d4.y], 1);
    atomicAdd(&deg[d4.z], 1);
    atomicAdd(&deg[d4.w], 1);
  } else {
    for (int i = i4; i < E; ++i) atomicAdd(&deg[dst[i]], 1);
  }
}

// ---------------- fused: wconv (0..127) + scan/bucket (128) + x->bf16 convert (129..) ----------------
// The 1-block scan's serial latency hides under the xconv stream.

__global__ __launch_bounds__(1024) void scanw_k(const int* __restrict__ deg,
                                                int* __restrict__ rowstart,
                                                unsigned short* __restrict__ nodeord, int n,
                                                const float* __restrict__ W1,
                                                const float* __restrict__ W2,
                                                unsigned short* __restrict__ W1t,
                                                unsigned short* __restrict__ W2t,
                                                const float* __restrict__ x,
                                                unsigned short* __restrict__ xs, int n8) {
  if (blockIdx.x < 128) {
    __shared__ float tile[64][65];
    int t = blockIdx.x;
    const float* W = W1;
    unsigned short* Wt = W1t;
    if (t >= 64) { t -= 64; W = W2; Wt = W2t; }
    int tr = (t >> 3) * 64;
    int tc = (t & 7) * 64;
    int tid = threadIdx.x;
    int c4 = (tid & 15) * 4, r = tid >> 4;  // r = 0..63
    float4 vv = *(const float4*)&W[(size_t)(tr + r) * 512 + tc + c4];
    tile[r][c4] = vv.x; tile[r][c4 + 1] = vv.y; tile[r][c4 + 2] = vv.z; tile[r][c4 + 3] = vv.w;
    __syncthreads();
    int nn = tid >> 4;
    int k0 = (tid & 15) * 4;
    ushort4 o;
    o.x = f2bf(tile[k0 + 0][nn]);
    o.y = f2bf(tile[k0 + 1][nn]);
    o.z = f2bf(tile[k0 + 2][nn]);
    o.w = f2bf(tile[k0 + 3][nn]);
    *(ushort4*)&Wt[(size_t)(tc + nn) * 512 + tr + k0] = o;
    return;
  }
  if (blockIdx.x > 128) {
    // x -> bf16 slice-major convert: xs[s][node][64]
    int i = (blockIdx.x - 129) * 1024 + threadIdx.x;
    if (i < n8) {
      int nd = i >> 6;
      int c = i & 63;
      int s = c >> 3;
      int off = c & 7;
      const float4* p = (const float4*)x + (size_t)i * 2;
      float4 u = p[0], v = p[1];
      s16x8 r;
      r[0] = (short)f2bf(u.x); r[1] = (short)f2bf(u.y);
      r[2] = (short)f2bf(u.z); r[3] = (short)f2bf(u.w);
      r[4] = (short)f2bf(v.x); r[5] = (short)f2bf(v.y);
      r[6] = (short)f2bf(v.z); r[7] = (short)f2bf(v.w);
      ((s16x8*)xs)[((size_t)s * n + nd) * 8 + off] = r;
    }
    return;
  }
  // ---- block 128: vectorized scan (4 elems/thread) + degree bucketing ----
  __shared__ int wsum[16];
  __shared__ int carry_s;
  __shared__ int hist[65];
  int tid = threadIdx.x;
  int lane = tid & 63, wid = tid >> 6;
  if (tid == 0) carry_s = 0;
  __syncthreads();
  for (int t0 = 0; t0 < n; t0 += 4096) {
    int base = t0 + tid * 4;
    int e0, e1, e2, e3;
    if (base + 3 < n) {
      int4 v4 = *(const int4*)&deg[base];
      e0 = v4.x; e1 = v4.y; e2 = v4.z; e3 = v4.w;
    } else {
      e0 = (base + 0 < n) ? deg[base + 0] : 0;
      e1 = (base + 1 < n) ? deg[base + 1] : 0;
      e2 = (base + 2 < n) ? deg[base + 2] : 0;
      e3 = (base + 3 < n) ? deg[base + 3] : 0;
    }
    int lsum = e0 + e1 + e2 + e3;
    int s = lsum;
#pragma unroll
    for (int off = 1; off < 64; off <<= 1) {
      int t = __shfl_up(s, off);
      if (lane >= off) s += t;
    }
    if (lane == 63) wsum[wid] = s;
    __syncthreads();
    if (wid == 0) {
      int ws = (lane < 16) ? wsum[lane] : 0;
#pragma unroll
      for (int off = 1; off < 16; off <<= 1) {
        int t = __shfl_up(ws, off);
        if (lane >= off) ws += t;
      }
      if (lane < 16) wsum[lane] = ws;
    }
    __syncthreads();
    int carry = carry_s;
    int wbase = (wid > 0) ? wsum[wid - 1] : 0;
    int pre = carry + wbase + (s - lsum);
    if (base + 0 < n) rowstart[base + 0] = pre;
    if (base + 1 < n) rowstart[base + 1] = pre + e0;
    if (base + 2 < n) rowstart[base + 2] = pre + e0 + e1;
    if (base + 3 < n) rowstart[base + 3] = pre + e0 + e1 + e2;
    int total = wsum[15];
    __syncthreads();
    if (tid == 0) carry_s = carry + total;
    __syncthreads();
  }
  if (tid == 0) rowstart[n] = carry_s;
  if (tid < 65) hist[tid] = 0;
  __syncthreads();
  for (int i = tid; i < n; i += 1024) atomicAdd(&hist[min(deg[i], 64)], 1);
  __syncthreads();
  if (tid == 0) {
    int run = 0;
    for (int b = 0; b < 65; ++b) { int c = hist[b]; hist[b] = run; run += c; }
  }
  __syncthreads();
  for (int i = tid; i < n; i += 1024) {
    int b = min(deg[i], 64);
    int pos = atomicAdd(&hist[b], 1);
    nodeord[pos] = (unsigned short)i;
  }
}

// ---------------- fill CSR (4 edges/thread) ----------------

__global__ __launch_bounds__(256) void fill_k(const int* __restrict__ src,
                                              const int* __restrict__ dst, int E,
                                              const int* __restrict__ rowstart,
                                              int* __restrict__ cursor,
                                              unsigned short* __restrict__ ep16) {
  int i4 = (blockIdx.x * 256 + threadIdx.x) * 4;
  if (i4 + 3 < E) {
    int4 d4 = *(const int4*)&dst[i4];
    int4 s4 = *(const int4*)&src[i4];
    int p0 = atomicAdd(&cursor[d4.x], 1); ep16[rowstart[d4.x] + p0] = (unsigned short)s4.x;
    int p1 = atomicAdd(&cursor[d4.y], 1); ep16[rowstart[d4.y] + p1] = (unsigned short)s4.y;
    int p2 = atomicAdd(&cursor[d4.z], 1); ep16[rowstart[d4.z] + p2] = (unsigned short)s4.z;
    int p3 = atomicAdd(&cursor[d4.w], 1); ep16[rowstart[d4.w] + p3] = (unsigned short)s4.w;
  } else {
    for (int i = i4; i < E; ++i) {
      int d = dst[i];
      int pos = atomicAdd(&cursor[d], 1);
      ep16[rowstart[d] + pos] = (unsigned short)src[i];
    }
  }
}

// ---------------- slice-per-XCD aggregation, batch-4, 8 blocks/CU ----------------

__global__ __launch_bounds__(256, 8) void agg_k(const unsigned short* __restrict__ xs,
                                                const int* __restrict__ rowstart,
                                                const unsigned short* __restrict__ ep16,
                                                const unsigned short* __restrict__ nodeord,
                                                unsigned short* __restrict__ h, int Nn) {
  int slice = blockIdx.x & 7;
  int nb = blockIdx.x >> 3;
  int wid = threadIdx.x >> 6, lane = threadIdx.x & 63;
  int g = lane >> 3, sub = lane & 7;
  int slot = (nb * 4 + wid) * 8 + g;
  int node = nodeord[slot];
  int beg = rowstart[node];
  int deg = rowstart[node + 1] - beg;
  int degm1 = max(deg - 1, 0);
  int dm = deg;
  dm = max(dm, __shfl_xor(dm, 8));
  dm = max(dm, __shfl_xor(dm, 16));
  dm = max(dm, __shfl_xor(dm, 32));
  const unsigned short* ep = ep16 + beg;
  const s16x8* sb = (const s16x8*)xs + (size_t)slice * Nn * 8;
  s16x8 own = sb[node * 8 + sub];
  pf2 acc[4];
#pragma unroll
  for (int q = 0; q < 4; ++q) {
    unsigned int d = (unsigned int)((const int*)&own)[q];
    acc[q].x = bitsf(d << 16);
    acc[q].y = bitsf(d & 0xffff0000u);
  }
  for (int t = 0; t < dm; t += 4) {
    s16x8 v[4];
    float m[4];
#pragma unroll
    for (int b = 0; b < 4; ++b) {
      int tt = t + b;
      int e = ep[min(tt, degm1)];
      m[b] = (tt < deg) ? 1.f : 0.f;
      v[b] = sb[e * 8 + sub];
    }
#pragma unroll
    for (int b = 0; b < 4; ++b) {
#pragma unroll
      for (int q = 0; q < 4; ++q) {
        unsigned int d = (unsigned int)((const int*)&v[b])[q];
        pf2 p;
        p.x = bitsf(d << 16);
        p.y = bitsf(d & 0xffff0000u);
        acc[q] += m[b] * p;  // v_pk_fma_f32
      }
    }
  }
  s16x8 r;
#pragma unroll
  for (int q = 0; q < 4; ++q) {
    r[q * 2 + 0] = (short)f2bf(acc[q].x);
    r[q * 2 + 1] = (short)f2bf(acc[q].y);
  }
  __builtin_nontemporal_store(r, (s16x8*)(h + (size_t)node * D_FEAT + slice * SLICE_D + sub * 8));
}

// ---------------- FUSED MLP v4: 1024 threads, pair-swizzled BK=32 staging ----------------

__global__ __launch_bounds__(1024, 1) void mlp_k(const unsigned short* __restrict__ A,
                                                 const unsigned short* __restrict__ W1t,
                                                 const unsigned short* __restrict__ W2t,
                                                 const float* __restrict__ b1,
                                                 const float* __restrict__ b2,
                                                 float* __restrict__ out, int M) {
  __shared__ unsigned short As[2][ROWS * 32];   // 10 KB
  __shared__ unsigned short Bs[2][512 * 32];    // 64 KB
  __shared__ unsigned short c1s[ROWS * 512];    // 80 KB  (total 154 KB)
  int tm = blockIdx.x;
  int tid = threadIdx.x;
  int wave = tid >> 6, lane = tid & 63;
  int lr = lane & 15, lh = lane >> 4;
  bool aw = tid < 320;  // A-staging threads (waves 0..4)

  auto ldschunk = [](int row, int c) {
    int p = row >> 1;
    return p * 8 + (((((row & 1) << 2) | c)) ^ (p & 7));
  };

  auto stage_b = [&](const unsigned short* Bt, int pb, int k0) {
#pragma unroll
    for (int ii = 0; ii < 2; ++ii) {
      int cb = ii * 1024 + tid;
      int p = cb >> 3;
      int s2 = (cb & 7) ^ (p & 7);
      int row = p * 2 + (s2 >> 2);
      int c = s2 & 3;
      async16(&Bs[pb][(size_t)(ii * 1024 + wave * 64) * 8], Bt + (size_t)row * 512 + k0 + c * 8);
    }
  };
  auto stage_a = [&](int pb, int k0) {
    if (aw) {
      int cb = tid;
      int p = cb >> 3;
      int s2 = (cb & 7) ^ (p & 7);
      int row = p * 2 + (s2 >> 2);
      int c = s2 & 3;
      int ga = min(tm * ROWS + row, M - 1);
      async16(&As[pb][(size_t)(wave * 64) * 8], A + (size_t)ga * 512 + k0 + c * 8);
    }
  };

  f32x4 zero = {0.f, 0.f, 0.f, 0.f};
  f32x4 acc[5][2];
#pragma unroll
  for (int rt = 0; rt < 5; ++rt)
#pragma unroll
    for (int ct = 0; ct < 2; ++ct) acc[rt][ct] = zero;

  // ---- phase 1: c1 = ReLU(A @ W1 + b1) ----
  stage_b(W1t, 0, 0);
  stage_a(0, 0);
#pragma unroll
  for (int t = 0; t < 16; ++t) {
    int pb = t & 1;
    if (t < 15) { stage_b(W1t, pb ^ 1, (t + 1) * 32); stage_a(pb ^ 1, (t + 1) * 32); }
    if (t < 15) {
      if (aw) asm volatile("s_waitcnt vmcnt(3)" ::: "memory");
      else    asm volatile("s_waitcnt vmcnt(2)" ::: "memory");
    } else {
      asm volatile("s_waitcnt vmcnt(0)" ::: "memory");
    }
    __builtin_amdgcn_s_barrier();
    s16x8 av[5], bv[2];
#pragma unroll
    for (int rt = 0; rt < 5; ++rt)
      av[rt] = *(const s16x8*)&As[pb][ldschunk(rt * 16 + lr, lh) * 8];
#pragma unroll
    for (int ct = 0; ct < 2; ++ct)
      bv[ct] = *(const s16x8*)&Bs[pb][ldschunk(wave * 32 + ct * 16 + lr, lh) * 8];
#pragma unroll
    for (int rt = 0; rt < 5; ++rt)
#pragma unroll
      for (int ct = 0; ct < 2; ++ct)
        acc[rt][ct] = __builtin_amdgcn_mfma_f32_16x16x32_bf16(av[rt], bv[ct], acc[rt][ct], 0, 0, 0);
    __builtin_amdgcn_s_barrier();
  }

  stage_b(W2t, 0, 0);

  // c1 -> LDS bf16; chunk XOR row&7 (8-slot, m97 pattern)
#pragma unroll
  for (int ct = 0; ct < 2; ++ct) {
    int col = wave * 32 + ct * 16 + lr;
    float bval = b1[col];
    int chunk = col >> 3;
#pragma unroll
    for (int rt = 0; rt < 5; ++rt) {
#pragma unroll
      for (int j = 0; j < 4; ++j) {
        int row = rt * 16 + lh * 4 + j;
        float v = fmaxf(acc[rt][ct][j] + bval, 0.f);
        c1s[row * 512 + ((chunk ^ (row & 7)) * 8) + (col & 7)] = f2bf(v);
      }
    }
  }
  __syncthreads();

  // ---- phase 2: out = c1 @ W2 + b2 ----
#pragma unroll
  for (int rt = 0; rt < 5; ++rt)
#pragma unroll
    for (int ct = 0; ct < 2; ++ct) acc[rt][ct] = zero;

#pragma unroll
  for (int t = 0; t < 16; ++t) {
    int pb = t & 1;
    if (t < 15) stage_b(W2t, pb ^ 1, (t + 1) * 32);
    if (t < 15) asm volatile("s_waitcnt vmcnt(2)" ::: "memory");
    else        asm volatile("s_waitcnt vmcnt(0)" ::: "memory");
    __builtin_amdgcn_s_barrier();
    s16x8 av[5], bv[2];
#pragma unroll
    for (int rt = 0; rt < 5; ++rt) {
      int row = rt * 16 + lr;
      av[rt] = *(const s16x8*)&c1s[row * 512 + (((t * 4 + lh) ^ (row & 7)) * 8)];
    }
#pragma unroll
    for (int ct = 0; ct < 2; ++ct)
      bv[ct] = *(const s16x8*)&Bs[pb][ldschunk(wave * 32 + ct * 16 + lr, lh) * 8];
#pragma unroll
    for (int rt = 0; rt < 5; ++rt)
#pragma unroll
      for (int ct = 0; ct < 2; ++ct)
        acc[rt][ct] = __builtin_amdgcn_mfma_f32_16x16x32_bf16(av[rt], bv[ct], acc[rt][ct], 0, 0, 0);
    __builtin_amdgcn_s_barrier();
  }

  // epilogue: C/D layout col=lane&15, row=(lane>>4)*4+j  [measured m89]
#pragma unroll
  for (int ct = 0; ct < 2; ++ct) {
    int col = wave * 32 + ct * 16 + lr;
    float bval = b2[col];
#pragma unroll
    for (int rt = 0; rt < 5; ++rt) {
#pragma unroll
      for (int j = 0; j < 4; ++j) {
        int row = tm * ROWS + rt * 16 + lh * 4 + j;
        if (row < M)
          __builtin_nontemporal_store(acc[rt][ct][j] + bval, &out[(size_t)row * 512 + col]);
      }
    }
  }
}

// ---------------- launch ----------------

extern "C" void kernel_launch(void* const* d_in, const int* in_sizes, int n_in,
                              void* d_out, int out_size, void* d_ws, size_t ws_size,
                              hipStream_t stream) {
  const float* x = (const float*)d_in[0];
  const int* ei = (const int*)d_in[1];
  const float* W1 = (const float*)d_in[2];
  const float* b1 = (const float*)d_in[3];
  const float* W2 = (const float*)d_in[4];
  const float* b2 = (const float*)d_in[5];
  const int N = in_sizes[0] / D_FEAT;  // 20000
  const int E = in_sizes[1] / 2;       // 640000
  const int* src = ei;
  const int* dst = ei + E;

  char* w = (char*)d_ws;
  auto alloc = [&](size_t bytes) {
    void* p = (void*)w;
    w += (bytes + 255) & ~(size_t)255;
    return p;
  };
  unsigned short* ep16 = (unsigned short*)alloc((size_t)E * 2 + 256);
  int* deg = (int*)alloc((size_t)N * 4);
  int* cursor = (int*)alloc((size_t)N * 4);
  int* rowstart = (int*)alloc((size_t)(N + 1) * 4);
  unsigned short* nodeord = (unsigned short*)alloc((size_t)N * 2);
  unsigned short* W1t = (unsigned short*)alloc((size_t)512 * 512 * 2);
  unsigned short* W2t = (unsigned short*)alloc((size_t)512 * 512 * 2);
  unsigned short* h = (unsigned short*)alloc((size_t)N * 512 * 2);  // h must NOT alias d_out
  // xs (slice-major bf16 x) = upper half of d_out; dead before mlp_k writes out.
  unsigned short* xs = (unsigned short*)d_out + (size_t)N * D_FEAT;

  size_t zbytes = (size_t)((char*)cursor - (char*)deg) + (size_t)N * 4;
  int zn16 = (int)(zbytes / 16);
  zero_k<<<(zn16 + 255) / 256, 256, 0, stream>>>((int4*)deg, zn16);
  int hb4 = (E / 4 + 255) / 256;  // 625
  hx_k<<<hb4, 256, 0, stream>>>(dst, E, deg);
  int n8 = N * D_FEAT / 8;                 // 1.28M
  int xbk = (n8 + 1023) / 1024;            // 1250
  scanw_k<<<129 + xbk, 1024, 0, stream>>>(deg, rowstart, nodeord, N, W1, W2, W1t, W2t,
                                          x, xs, n8);
  fill_k<<<hb4, 256, 0, stream>>>(src, dst, E, rowstart, cursor, ep16);
  agg_k<<<8 * (N / 32), 256, 0, stream>>>(xs, rowstart, ep16, nodeord, h, N);
  int mt = (N + ROWS - 1) / ROWS;  // 250
  mlp_k<<<mt, 1024, 0, stream>>>(h, W1t, W2t, b1, b2, (float*)d_out, N);
}

// Round 21
// 168.361 us; speedup vs baseline: 1.0277x; 1.0277x over previous
//
#include <hip/hip_runtime.h>
#include <hip/hip_bf16.h>

typedef __attribute__((ext_vector_type(8))) short s16x8;
typedef __attribute__((ext_vector_type(4))) float f32x4;
typedef __attribute__((ext_vector_type(2))) float pf2;

#define D_FEAT 512
#define SLICES 8
#define SLICE_D 64
#define ROWS 80   // rows per mlp block: grid = 20000/80 = 250 = 0.98 blocks/CU
#define NPT 20    // scan elements per thread (1024*20 = 20480 >= N)

__device__ __forceinline__ unsigned short f2bf(float f) {
  __hip_bfloat16 h = __float2bfloat16(f);
  return *reinterpret_cast<unsigned short*>(&h);
}

__device__ __forceinline__ float bitsf(unsigned int u) {
  union { unsigned int i; float f; } c;
  c.i = u;
  return c.f;
}

__device__ __forceinline__ void async16(void* lds, const void* g) {
  __builtin_amdgcn_global_load_lds(
      (const __attribute__((address_space(1))) void*)g,
      (__attribute__((address_space(3))) void*)lds, 16, 0, 0);
}

// ---------------- zero scratch ----------------

__global__ __launch_bounds__(256) void zero_k(int4* __restrict__ p, int n16) {
  int i = blockIdx.x * 256 + threadIdx.x;
  if (i < n16) p[i] = make_int4(0, 0, 0, 0);
}

// ---------------- prep: hist (0..624) | wconv (625..752) | xconv (753..) ----------------
// All three are mutually independent; the atomic-bound histogram hides under
// the 46MB x->bf16 convert stream instead of running alone.

__global__ __launch_bounds__(256) void prep_k(const int* __restrict__ dst, int E,
                                              int* __restrict__ deg,
                                              const float* __restrict__ W1,
                                              const float* __restrict__ W2,
                                              unsigned short* __restrict__ W1t,
                                              unsigned short* __restrict__ W2t,
                                              const float* __restrict__ x,
                                              unsigned short* __restrict__ xs,
                                              int n8, int Nn) {
  int bid = blockIdx.x;
  if (bid < 625) {
    int i4 = (bid * 256 + threadIdx.x) * 4;
    if (i4 + 3 < E) {
      int4 d4 = *(const int4*)&dst[i4];
      atomicAdd(&deg[d4.x], 1);
      atomicAdd(&deg[d4.y], 1);
      atomicAdd(&deg[d4.z], 1);
      atomicAdd(&deg[d4.w], 1);
    } else {
      for (int i = i4; i < E; ++i) atomicAdd(&deg[dst[i]], 1);
    }
    return;
  }
  if (bid < 753) {
    __shared__ float tile[64][65];
    int t = bid - 625;
    const float* W = W1;
    unsigned short* Wt = W1t;
    if (t >= 64) { t -= 64; W = W2; Wt = W2t; }
    int tr = (t >> 3) * 64;
    int tc = (t & 7) * 64;
    int tid = threadIdx.x;
    int c4 = (tid & 15) * 4, rg = tid >> 4;
#pragma unroll
    for (int rr = 0; rr < 64; rr += 16) {
      int r = rr + rg;
      float4 vv = *(const float4*)&W[(size_t)(tr + r) * 512 + tc + c4];
      tile[r][c4] = vv.x; tile[r][c4 + 1] = vv.y; tile[r][c4 + 2] = vv.z; tile[r][c4 + 3] = vv.w;
    }
    __syncthreads();
    int ch = tid & 15;
#pragma unroll
    for (int rr = 0; rr < 64; rr += 16) {
      int nn = rr + rg;
      int k0 = ch * 4;
      ushort4 o;
      o.x = f2bf(tile[k0 + 0][nn]);
      o.y = f2bf(tile[k0 + 1][nn]);
      o.z = f2bf(tile[k0 + 2][nn]);
      o.w = f2bf(tile[k0 + 3][nn]);
      *(ushort4*)&Wt[(size_t)(tc + nn) * 512 + tr + k0] = o;
    }
    return;
  }
  // xconv: xs[s][node][64] bf16 slice-major
  int i = (bid - 753) * 256 + threadIdx.x;
  if (i < n8) {
    int nd = i >> 6;
    int c = i & 63;
    int s = c >> 3;
    int off = c & 7;
    const float4* p = (const float4*)x + (size_t)i * 2;
    float4 u = p[0], v = p[1];
    s16x8 r;
    r[0] = (short)f2bf(u.x); r[1] = (short)f2bf(u.y);
    r[2] = (short)f2bf(u.z); r[3] = (short)f2bf(u.w);
    r[4] = (short)f2bf(v.x); r[5] = (short)f2bf(v.y);
    r[6] = (short)f2bf(v.z); r[7] = (short)f2bf(v.w);
    ((s16x8*)xs)[((size_t)s * Nn + nd) * 8 + off] = r;
  }
}

// ---------------- single-pass scan + degree bucketing (1 block, 1024 threads) ----------------
// Thread t owns elements [20t, 20t+20): serial local prefix in registers
// (fully unrolled -> no scratch), ONE block-scan of the 1024 thread sums.

__global__ __launch_bounds__(1024) void scan_k(const int* __restrict__ deg,
                                               int* __restrict__ rowstart,
                                               unsigned short* __restrict__ nodeord, int n) {
  __shared__ int wsum[16];
  __shared__ int hist[65];
  int tid = threadIdx.x;
  int lane = tid & 63, wid = tid >> 6;
  int base = tid * NPT;
  int e[NPT];
#pragma unroll
  for (int q = 0; q < NPT / 4; ++q) {
    int b4 = base + q * 4;
    if (b4 + 3 < n) {
      int4 v4 = *(const int4*)&deg[b4];
      e[q * 4 + 0] = v4.x; e[q * 4 + 1] = v4.y; e[q * 4 + 2] = v4.z; e[q * 4 + 3] = v4.w;
    } else {
      e[q * 4 + 0] = (b4 + 0 < n) ? deg[b4 + 0] : 0;
      e[q * 4 + 1] = (b4 + 1 < n) ? deg[b4 + 1] : 0;
      e[q * 4 + 2] = (b4 + 2 < n) ? deg[b4 + 2] : 0;
      e[q * 4 + 3] = (b4 + 3 < n) ? deg[b4 + 3] : 0;
    }
  }
  int lsum = 0;
#pragma unroll
  for (int q = 0; q < NPT; ++q) lsum += e[q];
  int s = lsum;
#pragma unroll
  for (int off = 1; off < 64; off <<= 1) {
    int t = __shfl_up(s, off);
    if (lane >= off) s += t;
  }
  if (lane == 63) wsum[wid] = s;
  __syncthreads();
  if (wid == 0) {
    int ws = (lane < 16) ? wsum[lane] : 0;
#pragma unroll
    for (int off = 1; off < 16; off <<= 1) {
      int t = __shfl_up(ws, off);
      if (lane >= off) ws += t;
    }
    if (lane < 16) wsum[lane] = ws;
  }
  __syncthreads();
  int pre = ((wid > 0) ? wsum[wid - 1] : 0) + (s - lsum);  // exclusive prefix at base
  // write prefixes: p[q] = pre + sum(e[0..q))
  int run = pre;
  int pfx[NPT];
#pragma unroll
  for (int q = 0; q < NPT; ++q) { pfx[q] = run; run += e[q]; }
#pragma unroll
  for (int q = 0; q < NPT / 4; ++q) {
    int b4 = base + q * 4;
    if (b4 + 3 < n) {
      *(int4*)&rowstart[b4] = make_int4(pfx[q * 4 + 0], pfx[q * 4 + 1], pfx[q * 4 + 2], pfx[q * 4 + 3]);
    } else {
      if (b4 + 0 < n) rowstart[b4 + 0] = pfx[q * 4 + 0];
      if (b4 + 1 < n) rowstart[b4 + 1] = pfx[q * 4 + 1];
      if (b4 + 2 < n) rowstart[b4 + 2] = pfx[q * 4 + 2];
      if (b4 + 3 < n) rowstart[b4 + 3] = pfx[q * 4 + 3];
    }
  }
  if (tid == 1023) rowstart[n] = run;  // total (thread 1023's running end)
  // ---- degree bucketing ----
  if (tid < 65) hist[tid] = 0;
  __syncthreads();
  for (int i = tid; i < n; i += 1024) atomicAdd(&hist[min(deg[i], 64)], 1);
  __syncthreads();
  if (tid == 0) {
    int r2 = 0;
    for (int b = 0; b < 65; ++b) { int c = hist[b]; hist[b] = r2; r2 += c; }
  }
  __syncthreads();
  for (int i = tid; i < n; i += 1024) {
    int b = min(deg[i], 64);
    int pos = atomicAdd(&hist[b], 1);
    nodeord[pos] = (unsigned short)i;
  }
}

// ---------------- fill CSR (4 edges/thread) ----------------

__global__ __launch_bounds__(256) void fill_k(const int* __restrict__ src,
                                              const int* __restrict__ dst, int E,
                                              const int* __restrict__ rowstart,
                                              int* __restrict__ cursor,
                                              unsigned short* __restrict__ ep16) {
  int i4 = (blockIdx.x * 256 + threadIdx.x) * 4;
  if (i4 + 3 < E) {
    int4 d4 = *(const int4*)&dst[i4];
    int4 s4 = *(const int4*)&src[i4];
    int p0 = atomicAdd(&cursor[d4.x], 1); ep16[rowstart[d4.x] + p0] = (unsigned short)s4.x;
    int p1 = atomicAdd(&cursor[d4.y], 1); ep16[rowstart[d4.y] + p1] = (unsigned short)s4.y;
    int p2 = atomicAdd(&cursor[d4.z], 1); ep16[rowstart[d4.z] + p2] = (unsigned short)s4.z;
    int p3 = atomicAdd(&cursor[d4.w], 1); ep16[rowstart[d4.w] + p3] = (unsigned short)s4.w;
  } else {
    for (int i = i4; i < E; ++i) {
      int d = dst[i];
      int pos = atomicAdd(&cursor[d], 1);
      ep16[rowstart[d] + pos] = (unsigned short)src[i];
    }
  }
}

// ---------------- slice-per-XCD aggregation, batch-4, 8 blocks/CU ----------------

__global__ __launch_bounds__(256, 8) void agg_k(const unsigned short* __restrict__ xs,
                                                const int* __restrict__ rowstart,
                                                const unsigned short* __restrict__ ep16,
                                                const unsigned short* __restrict__ nodeord,
                                                unsigned short* __restrict__ h, int Nn) {
  int slice = blockIdx.x & 7;
  int nb = blockIdx.x >> 3;
  int wid = threadIdx.x >> 6, lane = threadIdx.x & 63;
  int g = lane >> 3, sub = lane & 7;
  int slot = (nb * 4 + wid) * 8 + g;
  int node = nodeord[slot];
  int beg = rowstart[node];
  int deg = rowstart[node + 1] - beg;
  int degm1 = max(deg - 1, 0);
  int dm = deg;
  dm = max(dm, __shfl_xor(dm, 8));
  dm = max(dm, __shfl_xor(dm, 16));
  dm = max(dm, __shfl_xor(dm, 32));
  const unsigned short* ep = ep16 + beg;
  const s16x8* sb = (const s16x8*)xs + (size_t)slice * Nn * 8;
  s16x8 own = sb[node * 8 + sub];
  pf2 acc[4];
#pragma unroll
  for (int q = 0; q < 4; ++q) {
    unsigned int d = (unsigned int)((const int*)&own)[q];
    acc[q].x = bitsf(d << 16);
    acc[q].y = bitsf(d & 0xffff0000u);
  }
  for (int t = 0; t < dm; t += 4) {
    s16x8 v[4];
    float m[4];
#pragma unroll
    for (int b = 0; b < 4; ++b) {
      int tt = t + b;
      int e = ep[min(tt, degm1)];
      m[b] = (tt < deg) ? 1.f : 0.f;
      v[b] = sb[e * 8 + sub];
    }
#pragma unroll
    for (int b = 0; b < 4; ++b) {
#pragma unroll
      for (int q = 0; q < 4; ++q) {
        unsigned int d = (unsigned int)((const int*)&v[b])[q];
        pf2 p;
        p.x = bitsf(d << 16);
        p.y = bitsf(d & 0xffff0000u);
        acc[q] += m[b] * p;  // v_pk_fma_f32
      }
    }
  }
  s16x8 r;
#pragma unroll
  for (int q = 0; q < 4; ++q) {
    r[q * 2 + 0] = (short)f2bf(acc[q].x);
    r[q * 2 + 1] = (short)f2bf(acc[q].y);
  }
  __builtin_nontemporal_store(r, (s16x8*)(h + (size_t)node * D_FEAT + slice * SLICE_D + sub * 8));
}

// ---------------- FUSED MLP v4: 1024 threads, pair-swizzled BK=32 staging ----------------

__global__ __launch_bounds__(1024, 1) void mlp_k(const unsigned short* __restrict__ A,
                                                 const unsigned short* __restrict__ W1t,
                                                 const unsigned short* __restrict__ W2t,
                                                 const float* __restrict__ b1,
                                                 const float* __restrict__ b2,
                                                 float* __restrict__ out, int M) {
  __shared__ unsigned short As[2][ROWS * 32];   // 10 KB
  __shared__ unsigned short Bs[2][512 * 32];    // 64 KB
  __shared__ unsigned short c1s[ROWS * 512];    // 80 KB  (total 154 KB)
  int tm = blockIdx.x;
  int tid = threadIdx.x;
  int wave = tid >> 6, lane = tid & 63;
  int lr = lane & 15, lh = lane >> 4;
  bool aw = tid < 320;  // A-staging threads (waves 0..4)

  auto ldschunk = [](int row, int c) {
    int p = row >> 1;
    return p * 8 + (((((row & 1) << 2) | c)) ^ (p & 7));
  };

  auto stage_b = [&](const unsigned short* Bt, int pb, int k0) {
#pragma unroll
    for (int ii = 0; ii < 2; ++ii) {
      int cb = ii * 1024 + tid;
      int p = cb >> 3;
      int s2 = (cb & 7) ^ (p & 7);
      int row = p * 2 + (s2 >> 2);
      int c = s2 & 3;
      async16(&Bs[pb][(size_t)(ii * 1024 + wave * 64) * 8], Bt + (size_t)row * 512 + k0 + c * 8);
    }
  };
  auto stage_a = [&](int pb, int k0) {
    if (aw) {
      int cb = tid;
      int p = cb >> 3;
      int s2 = (cb & 7) ^ (p & 7);
      int row = p * 2 + (s2 >> 2);
      int c = s2 & 3;
      int ga = min(tm * ROWS + row, M - 1);
      async16(&As[pb][(size_t)(wave * 64) * 8], A + (size_t)ga * 512 + k0 + c * 8);
    }
  };

  f32x4 zero = {0.f, 0.f, 0.f, 0.f};
  f32x4 acc[5][2];
#pragma unroll
  for (int rt = 0; rt < 5; ++rt)
#pragma unroll
    for (int ct = 0; ct < 2; ++ct) acc[rt][ct] = zero;

  // ---- phase 1: c1 = ReLU(A @ W1 + b1) ----
  stage_b(W1t, 0, 0);
  stage_a(0, 0);
#pragma unroll
  for (int t = 0; t < 16; ++t) {
    int pb = t & 1;
    if (t < 15) { stage_b(W1t, pb ^ 1, (t + 1) * 32); stage_a(pb ^ 1, (t + 1) * 32); }
    if (t < 15) {
      if (aw) asm volatile("s_waitcnt vmcnt(3)" ::: "memory");
      else    asm volatile("s_waitcnt vmcnt(2)" ::: "memory");
    } else {
      asm volatile("s_waitcnt vmcnt(0)" ::: "memory");
    }
    __builtin_amdgcn_s_barrier();
    s16x8 av[5], bv[2];
#pragma unroll
    for (int rt = 0; rt < 5; ++rt)
      av[rt] = *(const s16x8*)&As[pb][ldschunk(rt * 16 + lr, lh) * 8];
#pragma unroll
    for (int ct = 0; ct < 2; ++ct)
      bv[ct] = *(const s16x8*)&Bs[pb][ldschunk(wave * 32 + ct * 16 + lr, lh) * 8];
#pragma unroll
    for (int rt = 0; rt < 5; ++rt)
#pragma unroll
      for (int ct = 0; ct < 2; ++ct)
        acc[rt][ct] = __builtin_amdgcn_mfma_f32_16x16x32_bf16(av[rt], bv[ct], acc[rt][ct], 0, 0, 0);
    __builtin_amdgcn_s_barrier();
  }

  stage_b(W2t, 0, 0);

  // c1 -> LDS bf16; chunk XOR row&7 (8-slot, m97 pattern)
#pragma unroll
  for (int ct = 0; ct < 2; ++ct) {
    int col = wave * 32 + ct * 16 + lr;
    float bval = b1[col];
    int chunk = col >> 3;
#pragma unroll
    for (int rt = 0; rt < 5; ++rt) {
#pragma unroll
      for (int j = 0; j < 4; ++j) {
        int row = rt * 16 + lh * 4 + j;
        float v = fmaxf(acc[rt][ct][j] + bval, 0.f);
        c1s[row * 512 + ((chunk ^ (row & 7)) * 8) + (col & 7)] = f2bf(v);
      }
    }
  }
  __syncthreads();

  // ---- phase 2: out = c1 @ W2 + b2 ----
#pragma unroll
  for (int rt = 0; rt < 5; ++rt)
#pragma unroll
    for (int ct = 0; ct < 2; ++ct) acc[rt][ct] = zero;

#pragma unroll
  for (int t = 0; t < 16; ++t) {
    int pb = t & 1;
    if (t < 15) stage_b(W2t, pb ^ 1, (t + 1) * 32);
    if (t < 15) asm volatile("s_waitcnt vmcnt(2)" ::: "memory");
    else        asm volatile("s_waitcnt vmcnt(0)" ::: "memory");
    __builtin_amdgcn_s_barrier();
    s16x8 av[5], bv[2];
#pragma unroll
    for (int rt = 0; rt < 5; ++rt) {
      int row = rt * 16 + lr;
      av[rt] = *(const s16x8*)&c1s[row * 512 + (((t * 4 + lh) ^ (row & 7)) * 8)];
    }
#pragma unroll
    for (int ct = 0; ct < 2; ++ct)
      bv[ct] = *(const s16x8*)&Bs[pb][ldschunk(wave * 32 + ct * 16 + lr, lh) * 8];
#pragma unroll
    for (int rt = 0; rt < 5; ++rt)
#pragma unroll
      for (int ct = 0; ct < 2; ++ct)
        acc[rt][ct] = __builtin_amdgcn_mfma_f32_16x16x32_bf16(av[rt], bv[ct], acc[rt][ct], 0, 0, 0);
    __builtin_amdgcn_s_barrier();
  }

  // epilogue: C/D layout col=lane&15, row=(lane>>4)*4+j  [measured m89]
#pragma unroll
  for (int ct = 0; ct < 2; ++ct) {
    int col = wave * 32 + ct * 16 + lr;
    float bval = b2[col];
#pragma unroll
    for (int rt = 0; rt < 5; ++rt) {
#pragma unroll
      for (int j = 0; j < 4; ++j) {
        int row = tm * ROWS + rt * 16 + lh * 4 + j;
        if (row < M)
          __builtin_nontemporal_store(acc[rt][ct][j] + bval, &out[(size_t)row * 512 + col]);
      }
    }
  }
}

// ---------------- launch ----------------

extern "C" void kernel_launch(void* const* d_in, const int* in_sizes, int n_in,
                              void* d_out, int out_size, void* d_ws, size_t ws_size,
                              hipStream_t stream) {
  const float* x = (const float*)d_in[0];
  const int* ei = (const int*)d_in[1];
  const float* W1 = (const float*)d_in[2];
  const float* b1 = (const float*)d_in[3];
  const float* W2 = (const float*)d_in[4];
  const float* b2 = (const float*)d_in[5];
  const int N = in_sizes[0] / D_FEAT;  // 20000
  const int E = in_sizes[1] / 2;       // 640000
  const int* src = ei;
  const int* dst = ei + E;

  char* w = (char*)d_ws;
  auto alloc = [&](size_t bytes) {
    void* p = (void*)w;
    w += (bytes + 255) & ~(size_t)255;
    return p;
  };
  unsigned short* ep16 = (unsigned short*)alloc((size_t)E * 2 + 256);
  int* deg = (int*)alloc((size_t)N * 4);
  int* cursor = (int*)alloc((size_t)N * 4);
  int* rowstart = (int*)alloc((size_t)(N + 1) * 4);
  unsigned short* nodeord = (unsigned short*)alloc((size_t)N * 2);
  unsigned short* W1t = (unsigned short*)alloc((size_t)512 * 512 * 2);
  unsigned short* W2t = (unsigned short*)alloc((size_t)512 * 512 * 2);
  unsigned short* h = (unsigned short*)alloc((size_t)N * 512 * 2);  // h must NOT alias d_out
  // xs (slice-major bf16 x) = upper half of d_out; dead before mlp_k writes out.
  unsigned short* xs = (unsigned short*)d_out + (size_t)N * D_FEAT;

  size_t zbytes = (size_t)((char*)cursor - (char*)deg) + (size_t)N * 4;
  int zn16 = (int)(zbytes / 16);
  zero_k<<<(zn16 + 255) / 256, 256, 0, stream>>>((int4*)deg, zn16);
  int n8 = N * D_FEAT / 8;              // 1.28M
  int xbk = (n8 + 255) / 256;           // 5000
  prep_k<<<753 + xbk, 256, 0, stream>>>(dst, E, deg, W1, W2, W1t, W2t, x, xs, n8, N);
  scan_k<<<1, 1024, 0, stream>>>(deg, rowstart, nodeord, N);
  int hb4 = (E / 4 + 255) / 256;        // 625
  fill_k<<<hb4, 256, 0, stream>>>(src, dst, E, rowstart, cursor, ep16);
  agg_k<<<8 * (N / 32), 256, 0, stream>>>(xs, rowstart, ep16, nodeord, h, N);
  int mt = (N + ROWS - 1) / ROWS;       // 250
  mlp_k<<<mt, 1024, 0, stream>>>(h, W1t, W2t, b1, b2, (float*)d_out, N);
}